// Round 1
// baseline (323.982 us; speedup 1.0000x reference)
//
#include <hip/hip_runtime.h>
#include <cstdint>
#include <cstddef>

typedef unsigned long long u64;
typedef unsigned int u32;

#define A_TOT   8400
#define NCLS    80
#define KSLOT   1024
#define NCHUNK  9
#define TOPK_N  1000
#define MAXDET  300
#define OUT_STRIDE (MAXDET * 6)

// ---------- helpers ----------

// stepwise f32 sigmoid with correctly-rounded f32 exp (via f64):
// e = fl32(exp(-x)); s = 1/(1+e)   -- replicates np-f32 semantics
__device__ __forceinline__ float sig32(float x) {
#pragma clang fp contract(off)
    float e = (float)exp(-(double)x);
    float t = 1.0f + e;
    return 1.0f / t;
}

__device__ __forceinline__ u32 key_hi_from_score(float s) {
    u32 u = __float_as_uint(s);
    return (u & 0x80000000u) ? ~u : (u | 0x80000000u);
}
__device__ __forceinline__ float score_from_key_hi(u32 t) {
    u32 u = (t & 0x80000000u) ? (t ^ 0x80000000u) : ~t;
    return __uint_as_float(u);
}

// ---------- 1. decode: conf/argmax -> sort key ----------
__global__ void k_decode(const float* __restrict__ preds, u64* __restrict__ key_raw) {
#pragma clang fp contract(off)
    int a = blockIdx.x * blockDim.x + threadIdx.x;
    int b = blockIdx.y;
    if (a >= A_TOT) return;
    const float* p = preds + ((size_t)b * 144 + 64) * A_TOT + a;

    float m = -3.0e38f, m2 = -3.0e38f;
    int jm = 0;
#pragma unroll 4
    for (int c = 0; c < NCLS; ++c) {
        float v = p[(size_t)c * A_TOT];
        if (v > m) { m2 = m; m = v; jm = c; }
        else if (v > m2) { m2 = v; }
    }

    float conf;
    int cls = jm;
    if ((m - m2) < 1e-4f || m > 7.0f) {
        // slow exact path: argmax over f32 sigmoid values (first-index ties)
        float sb = -1.0f; int jb = 0;
        for (int c = 0; c < NCLS; ++c) {
            float s = sig32(p[(size_t)c * A_TOT]);
            if (s > sb) { sb = s; jb = c; }
        }
        conf = sb; cls = jb;
    } else {
        conf = sig32(m);
    }

    float score = (conf > 0.25f) ? conf : -1.0f;
    u32 hi = key_hi_from_score(score);
    u32 lo = ((0x3FFFu - (u32)a) << 7) | (u32)cls;   // idx asc tie-break + carry cls
    key_raw[(size_t)b * A_TOT + a] = ((u64)hi << 32) | lo;
}

// ---------- 2a. bitonic sort of 1024-chunks (descending) ----------
__global__ __launch_bounds__(1024) void k_chunksort(const u64* __restrict__ key_raw,
                                                    u64* __restrict__ key_sorted) {
    __shared__ u64 s[KSLOT];
    int b = blockIdx.y, ch = blockIdx.x, t = threadIdx.x;
    int a = ch * KSLOT + t;
    s[t] = (a < A_TOT) ? key_raw[(size_t)b * A_TOT + a] : 0ull;
    __syncthreads();
    for (int k = 2; k <= KSLOT; k <<= 1) {
        for (int j = k >> 1; j > 0; j >>= 1) {
            int ixj = t ^ j;
            if (ixj > t) {
                u64 x = s[t], y = s[ixj];
                bool descBlock = ((t & k) == 0);
                bool sw = descBlock ? (x < y) : (x > y);
                if (sw) { s[t] = y; s[ixj] = x; }
            }
            __syncthreads();
        }
    }
    key_sorted[((size_t)b * NCHUNK + ch) * KSLOT + t] = s[t];
}

// ---------- 2b. merge 9 sorted chunks -> top-1024 descending ----------
__global__ __launch_bounds__(1024) void k_merge(const u64* __restrict__ key_sorted,
                                                u64* __restrict__ topk) {
    __shared__ u64 R[KSLOT];
    __shared__ u64 C[KSLOT];
    int b = blockIdx.x, t = threadIdx.x;
    R[t] = key_sorted[((size_t)b * NCHUNK) * KSLOT + t];
    for (int ch = 1; ch < NCHUNK; ++ch) {
        C[t] = key_sorted[((size_t)b * NCHUNK + ch) * KSLOT + t];
        __syncthreads();
        u64 r = R[t];
        u64 c = C[(KSLOT - 1) - t];
        u64 nv = (r > c) ? r : c;       // top-1024 of union, bitonic
        __syncthreads();
        R[t] = nv;
        __syncthreads();
        for (int j = KSLOT >> 1; j >= 1; j >>= 1) {   // bitonic merge, descending
            int ixj = t ^ j;
            if (ixj > t) {
                u64 x = R[t], y = R[ixj];
                if (x < y) { R[t] = y; R[ixj] = x; }
            }
            __syncthreads();
        }
    }
    topk[(size_t)b * KSLOT + t] = R[t];
}

// ---------- 3. prep: DFL box decode for top slots, offset boxes + areas ----------
__global__ void k_prep(const float* __restrict__ preds, const u64* __restrict__ topk,
                       float* __restrict__ tb, float* __restrict__ ob,
                       float* __restrict__ area, u32* __restrict__ validf) {
#pragma clang fp contract(off)
    int slot = blockIdx.x * blockDim.x + threadIdx.x;
    int b = blockIdx.y;
    if (slot >= KSLOT) return;
    size_t si = (size_t)b * KSLOT + slot;
    u64 key = topk[si];
    u32 hi = (u32)(key >> 32);
    u32 lo = (u32)key;
    bool valid = (slot < TOPK_N) && (hi & 0x80000000u);
    if (!valid) {
        tb[si*4+0]=0.f; tb[si*4+1]=0.f; tb[si*4+2]=0.f; tb[si*4+3]=0.f;
        ob[si*4+0]=0.f; ob[si*4+1]=0.f; ob[si*4+2]=0.f; ob[si*4+3]=0.f;
        area[si] = 0.f; validf[si] = 0u;
        return;
    }
    int a   = 0x3FFF - (int)((lo >> 7) & 0x3FFFu);
    int cls = (int)(lo & 0x7Fu);

    int row, col; float stride;
    if (a < 6400)      { row = a / 80;          col = a % 80;          stride = 8.0f; }
    else if (a < 8000) { int aa = a - 6400; row = aa / 40; col = aa % 40; stride = 16.0f; }
    else               { int aa = a - 8000; row = aa / 20; col = aa % 20; stride = 32.0f; }
    float ax = (float)col + 0.5f;
    float ay = (float)row + 0.5f;

    const float* p = preds + (size_t)b * 144 * A_TOT + a;
    float d[4];
#pragma unroll
    for (int q = 0; q < 4; ++q) {
        float x[16];
#pragma unroll
        for (int r = 0; r < 16; ++r) x[r] = p[(size_t)(q*16 + r) * A_TOT];
        float mx = x[0];
#pragma unroll
        for (int r = 1; r < 16; ++r) mx = fmaxf(mx, x[r]);
        float e[16], s = 0.f;
#pragma unroll
        for (int r = 0; r < 16; ++r) { e[r] = expf(x[r] - mx); s = s + e[r]; }
        float dd = 0.f;
#pragma unroll
        for (int r = 0; r < 16; ++r) { float pr = e[r] / s; dd = dd + pr * (float)r; }
        d[q] = dd;
    }
    // exact reference op order
    float x1 = ax - d[0], y1 = ay - d[1];
    float x2 = ax + d[2], y2 = ay + d[3];
    float cx = (x1 + x2) / 2.0f, cy = (y1 + y2) / 2.0f;
    float w  = x2 - x1,          h  = y2 - y1;
    float CX = cx * stride, CY = cy * stride, W = w * stride, H = h * stride;
    float bx1 = CX - W / 2.0f, by1 = CY - H / 2.0f;
    float bx2 = CX + W / 2.0f, by2 = CY + H / 2.0f;
    tb[si*4+0] = bx1; tb[si*4+1] = by1; tb[si*4+2] = bx2; tb[si*4+3] = by2;

    float off = (float)cls * 7680.0f;
    float o0 = bx1 + off, o1 = by1 + off, o2 = bx2 + off, o3 = by2 + off;
    ob[si*4+0] = o0; ob[si*4+1] = o1; ob[si*4+2] = o2; ob[si*4+3] = o3;
    area[si] = (o2 - o0) * (o3 - o1);
    validf[si] = 1u;
}

// ---------- 4. suppression bitmask matrix: row i, bits j>i with iou>thr ----------
__global__ void k_matrix(const float* __restrict__ ob, const float* __restrict__ area,
                         u64* __restrict__ masks) {
#pragma clang fp contract(off)
    __shared__ float4 sob[KSLOT];
    __shared__ float  sar[KSLOT];
    int b = blockIdx.y, rblk = blockIdx.x, tid = threadIdx.x;
    const float4* gob = (const float4*)(ob + (size_t)b * KSLOT * 4);
    const float*  gar = area + (size_t)b * KSLOT;
    for (int i = tid; i < KSLOT; i += blockDim.x) { sob[i] = gob[i]; sar[i] = gar[i]; }
    __syncthreads();

    for (int task = tid; task < 64 * 16; task += blockDim.x) {
        int i = rblk * 64 + (task >> 4);
        int w = task & 15;
        u64 mword = 0ull;
        if ((w << 6) + 63 > i) {
            float4 bi = sob[i];
            float Ai = sar[i];
            for (int bit = 0; bit < 64; ++bit) {
                int j = (w << 6) + bit;
                if (j <= i) continue;
                float4 bj = sob[j];
                float lt0 = fmaxf(bi.x, bj.x);
                float lt1 = fmaxf(bi.y, bj.y);
                float rb0 = fminf(bi.z, bj.z);
                float rb1 = fminf(bi.w, bj.w);
                float ww = fmaxf(rb0 - lt0, 0.0f);
                float hh = fmaxf(rb1 - lt1, 0.0f);
                float inter = ww * hh;
                float den = ((Ai + sar[j]) - inter) + 1e-7f;
                float iou = inter / den;
                if (iou > 0.45f) mword |= (1ull << bit);
            }
        }
        masks[((size_t)b * KSLOT + i) * 16 + w] = mword;
    }
}

// ---------- 5. greedy scan (one wave per batch) ----------
__global__ void k_scan(const u64* __restrict__ masks, const u32* __restrict__ validf,
                       u64* __restrict__ keep) {
    __shared__ u64 sm[64][16];
    __shared__ u32 sv[64];
    int b = blockIdx.x, lane = threadIdx.x;
    u64 removed = 0ull, keepw = 0ull;
    for (int ch = 0; ch < 16; ++ch) {
        for (int w = 0; w < 16; ++w)
            sm[lane][w] = masks[((size_t)b * KSLOT + ch * 64 + lane) * 16 + w];
        sv[lane] = validf[(size_t)b * KSLOT + ch * 64 + lane];
        __syncthreads();
        for (int il = 0; il < 64; ++il) {
            u64 rw = __shfl(removed, ch);       // word index of i == ch
            bool sup = (rw >> il) & 1ull;
            bool v = (sv[il] != 0u);
            if (v && !sup) {
                if (lane == ch) keepw |= (1ull << il);
                if (lane < 16) removed |= sm[il][lane];
            }
        }
        __syncthreads();
    }
    if (lane < 16) keep[(size_t)b * 16 + lane] = keepw;
}

// ---------- 6. finalize: compact kept (ordered) into first 300 rows ----------
__global__ __launch_bounds__(1024) void k_final(const u64* __restrict__ keep,
                                                const u64* __restrict__ topk,
                                                const float* __restrict__ tb,
                                                float* __restrict__ out) {
    __shared__ u64 kw[16];
    __shared__ int pref[16];
    int b = blockIdx.x, t = threadIdx.x;
    float* ob_ = out + (size_t)b * OUT_STRIDE;
    for (int i = t; i < OUT_STRIDE; i += blockDim.x) ob_[i] = 0.0f;
    if (t < 16) kw[t] = keep[(size_t)b * 16 + t];
    __syncthreads();
    if (t == 0) {
        int s = 0;
        for (int w = 0; w < 16; ++w) { pref[w] = s; s += __popcll(kw[w]); }
    }
    __syncthreads();
    int w = t >> 6, bit = t & 63;
    bool kp = (kw[w] >> bit) & 1ull;
    if (kp) {
        u64 below = (bit == 0) ? 0ull : (kw[w] & ((1ull << bit) - 1ull));
        int rank = pref[w] + __popcll(below);
        if (rank < MAXDET) {
            size_t si = (size_t)b * KSLOT + t;
            u64 key = topk[si];
            u32 hi = (u32)(key >> 32);
            u32 lo = (u32)key;
            float score = score_from_key_hi(hi);
            float clsf = (float)(lo & 0x7Fu);
            float* o = ob_ + rank * 6;
            o[0] = tb[si*4+0]; o[1] = tb[si*4+1];
            o[2] = tb[si*4+2]; o[3] = tb[si*4+3];
            o[4] = score; o[5] = clsf;
        }
    }
}

// ---------- launch ----------
extern "C" void kernel_launch(void* const* d_in, const int* in_sizes, int n_in,
                              void* d_out, int out_size, void* d_ws, size_t ws_size,
                              hipStream_t stream) {
    const float* preds = (const float*)d_in[0];
    float* out = (float*)d_out;
    int B = in_sizes[0] / (144 * A_TOT);

    char* ws = (char*)d_ws;
    size_t off = 0;
    u64* key_raw    = (u64*)(ws + off); off += (size_t)B * A_TOT * 8;
    u64* key_sorted = (u64*)(ws + off); off += (size_t)B * NCHUNK * KSLOT * 8;
    u64* topk       = (u64*)(ws + off); off += (size_t)B * KSLOT * 8;
    float* tb       = (float*)(ws + off); off += (size_t)B * KSLOT * 4 * 4;
    float* obuf     = (float*)(ws + off); off += (size_t)B * KSLOT * 4 * 4;
    float* area     = (float*)(ws + off); off += (size_t)B * KSLOT * 4;
    u32* validf     = (u32*)(ws + off); off += (size_t)B * KSLOT * 4;
    u64* masks      = (u64*)(ws + off); off += (size_t)B * KSLOT * 16 * 8;
    u64* keep       = (u64*)(ws + off); off += (size_t)B * 16 * 8;

    k_decode<<<dim3((A_TOT + 255) / 256, B), 256, 0, stream>>>(preds, key_raw);
    k_chunksort<<<dim3(NCHUNK, B), KSLOT, 0, stream>>>(key_raw, key_sorted);
    k_merge<<<B, KSLOT, 0, stream>>>(key_sorted, topk);
    k_prep<<<dim3(KSLOT / 256, B), 256, 0, stream>>>(preds, topk, tb, obuf, area, validf);
    k_matrix<<<dim3(16, B), 256, 0, stream>>>(obuf, area, masks);
    k_scan<<<B, 64, 0, stream>>>(masks, validf, keep);
    k_final<<<B, 1024, 0, stream>>>(keep, topk, tb, out);
}

// Round 2
// 248.842 us; speedup vs baseline: 1.3020x; 1.3020x over previous
//
#include <hip/hip_runtime.h>
#include <cstdint>
#include <cstddef>

typedef unsigned long long u64;
typedef unsigned int u32;

#define A_TOT   8400
#define NCLS    80
#define KSLOT   1024
#define NCHUNK  9
#define TOPK_N  1000
#define MAXDET  300
#define OUT_STRIDE (MAXDET * 6)

// ---------- helpers ----------

// stepwise f32 sigmoid with correctly-rounded f32 exp (via f64):
// e = fl32(exp(-x)); s = 1/(1+e)   -- replicates np-f32 semantics
__device__ __forceinline__ float sig32(float x) {
#pragma clang fp contract(off)
    float e = (float)exp(-(double)x);
    float t = 1.0f + e;
    return 1.0f / t;
}

__device__ __forceinline__ u32 key_hi_from_score(float s) {
    u32 u = __float_as_uint(s);
    return (u & 0x80000000u) ? ~u : (u | 0x80000000u);
}
__device__ __forceinline__ float score_from_key_hi(u32 t) {
    u32 u = (t & 0x80000000u) ? (t ^ 0x80000000u) : ~t;
    return __uint_as_float(u);
}

// ---------- 1. decode: conf/argmax -> sort key ----------
__global__ void k_decode(const float* __restrict__ preds, u64* __restrict__ key_raw) {
#pragma clang fp contract(off)
    int a = blockIdx.x * blockDim.x + threadIdx.x;
    int b = blockIdx.y;
    if (a >= A_TOT) return;
    const float* p = preds + ((size_t)b * 144 + 64) * A_TOT + a;

    float m = -3.0e38f, m2 = -3.0e38f;
    int jm = 0;
#pragma unroll 4
    for (int c = 0; c < NCLS; ++c) {
        float v = p[(size_t)c * A_TOT];
        if (v > m) { m2 = m; m = v; jm = c; }
        else if (v > m2) { m2 = v; }
    }

    float conf;
    int cls = jm;
    if ((m - m2) < 1e-4f || m > 7.0f) {
        // slow exact path: argmax over f32 sigmoid values (first-index ties)
        float sb = -1.0f; int jb = 0;
        for (int c = 0; c < NCLS; ++c) {
            float s = sig32(p[(size_t)c * A_TOT]);
            if (s > sb) { sb = s; jb = c; }
        }
        conf = sb; cls = jb;
    } else {
        conf = sig32(m);
    }

    float score = (conf > 0.25f) ? conf : -1.0f;
    u32 hi = key_hi_from_score(score);
    u32 lo = ((0x3FFFu - (u32)a) << 7) | (u32)cls;   // idx asc tie-break + carry cls
    key_raw[(size_t)b * A_TOT + a] = ((u64)hi << 32) | lo;
}

// ---------- 2a. bitonic sort of 1024-chunks (descending) ----------
__global__ __launch_bounds__(1024) void k_chunksort(const u64* __restrict__ key_raw,
                                                    u64* __restrict__ key_sorted) {
    __shared__ u64 s[KSLOT];
    int b = blockIdx.y, ch = blockIdx.x, t = threadIdx.x;
    int a = ch * KSLOT + t;
    s[t] = (a < A_TOT) ? key_raw[(size_t)b * A_TOT + a] : 0ull;
    __syncthreads();
    for (int k = 2; k <= KSLOT; k <<= 1) {
        for (int j = k >> 1; j > 0; j >>= 1) {
            int ixj = t ^ j;
            if (ixj > t) {
                u64 x = s[t], y = s[ixj];
                bool descBlock = ((t & k) == 0);
                bool sw = descBlock ? (x < y) : (x > y);
                if (sw) { s[t] = y; s[ixj] = x; }
            }
            __syncthreads();
        }
    }
    key_sorted[((size_t)b * NCHUNK + ch) * KSLOT + t] = s[t];
}

// ---------- 2b. merge 9 sorted chunks -> top-1024 descending ----------
__global__ __launch_bounds__(1024) void k_merge(const u64* __restrict__ key_sorted,
                                                u64* __restrict__ topk) {
    __shared__ u64 R[KSLOT];
    __shared__ u64 C[KSLOT];
    int b = blockIdx.x, t = threadIdx.x;
    R[t] = key_sorted[((size_t)b * NCHUNK) * KSLOT + t];
    for (int ch = 1; ch < NCHUNK; ++ch) {
        C[t] = key_sorted[((size_t)b * NCHUNK + ch) * KSLOT + t];
        __syncthreads();
        u64 r = R[t];
        u64 c = C[(KSLOT - 1) - t];
        u64 nv = (r > c) ? r : c;       // top-1024 of union, bitonic
        __syncthreads();
        R[t] = nv;
        __syncthreads();
        for (int j = KSLOT >> 1; j >= 1; j >>= 1) {   // bitonic merge, descending
            int ixj = t ^ j;
            if (ixj > t) {
                u64 x = R[t], y = R[ixj];
                if (x < y) { R[t] = y; R[ixj] = x; }
            }
            __syncthreads();
        }
    }
    topk[(size_t)b * KSLOT + t] = R[t];
}

// ---------- 3. prep: DFL box decode for top slots, offset boxes + areas ----------
__global__ void k_prep(const float* __restrict__ preds, const u64* __restrict__ topk,
                       float* __restrict__ tb, float* __restrict__ ob,
                       float* __restrict__ area, u32* __restrict__ validf) {
#pragma clang fp contract(off)
    int slot = blockIdx.x * blockDim.x + threadIdx.x;
    int b = blockIdx.y;
    if (slot >= KSLOT) return;
    size_t si = (size_t)b * KSLOT + slot;
    u64 key = topk[si];
    u32 hi = (u32)(key >> 32);
    u32 lo = (u32)key;
    bool valid = (slot < TOPK_N) && (hi & 0x80000000u);
    if (!valid) {
        tb[si*4+0]=0.f; tb[si*4+1]=0.f; tb[si*4+2]=0.f; tb[si*4+3]=0.f;
        ob[si*4+0]=0.f; ob[si*4+1]=0.f; ob[si*4+2]=0.f; ob[si*4+3]=0.f;
        area[si] = 0.f; validf[si] = 0u;
        return;
    }
    int a   = 0x3FFF - (int)((lo >> 7) & 0x3FFFu);
    int cls = (int)(lo & 0x7Fu);

    int row, col; float stride;
    if (a < 6400)      { row = a / 80;          col = a % 80;          stride = 8.0f; }
    else if (a < 8000) { int aa = a - 6400; row = aa / 40; col = aa % 40; stride = 16.0f; }
    else               { int aa = a - 8000; row = aa / 20; col = aa % 20; stride = 32.0f; }
    float ax = (float)col + 0.5f;
    float ay = (float)row + 0.5f;

    const float* p = preds + (size_t)b * 144 * A_TOT + a;
    float d[4];
#pragma unroll
    for (int q = 0; q < 4; ++q) {
        float x[16];
#pragma unroll
        for (int r = 0; r < 16; ++r) x[r] = p[(size_t)(q*16 + r) * A_TOT];
        float mx = x[0];
#pragma unroll
        for (int r = 1; r < 16; ++r) mx = fmaxf(mx, x[r]);
        float e[16], s = 0.f;
#pragma unroll
        for (int r = 0; r < 16; ++r) { e[r] = expf(x[r] - mx); s = s + e[r]; }
        float dd = 0.f;
#pragma unroll
        for (int r = 0; r < 16; ++r) { float pr = e[r] / s; dd = dd + pr * (float)r; }
        d[q] = dd;
    }
    // exact reference op order
    float x1 = ax - d[0], y1 = ay - d[1];
    float x2 = ax + d[2], y2 = ay + d[3];
    float cx = (x1 + x2) / 2.0f, cy = (y1 + y2) / 2.0f;
    float w  = x2 - x1,          h  = y2 - y1;
    float CX = cx * stride, CY = cy * stride, W = w * stride, H = h * stride;
    float bx1 = CX - W / 2.0f, by1 = CY - H / 2.0f;
    float bx2 = CX + W / 2.0f, by2 = CY + H / 2.0f;
    tb[si*4+0] = bx1; tb[si*4+1] = by1; tb[si*4+2] = bx2; tb[si*4+3] = by2;

    float off = (float)cls * 7680.0f;
    float o0 = bx1 + off, o1 = by1 + off, o2 = bx2 + off, o3 = by2 + off;
    ob[si*4+0] = o0; ob[si*4+1] = o1; ob[si*4+2] = o2; ob[si*4+3] = o3;
    area[si] = (o2 - o0) * (o3 - o1);
    validf[si] = 1u;
}

// ---------- 4. suppression bitmask matrix: row i, bits j>i with iou>thr ----------
__global__ void k_matrix(const float* __restrict__ ob, const float* __restrict__ area,
                         u64* __restrict__ masks) {
#pragma clang fp contract(off)
    __shared__ float4 sob[KSLOT];
    __shared__ float  sar[KSLOT];
    int b = blockIdx.y, rblk = blockIdx.x, tid = threadIdx.x;
    const float4* gob = (const float4*)(ob + (size_t)b * KSLOT * 4);
    const float*  gar = area + (size_t)b * KSLOT;
    for (int i = tid; i < KSLOT; i += blockDim.x) { sob[i] = gob[i]; sar[i] = gar[i]; }
    __syncthreads();

    for (int task = tid; task < 64 * 16; task += blockDim.x) {
        int i = rblk * 64 + (task >> 4);
        int w = task & 15;
        u64 mword = 0ull;
        if ((w << 6) + 63 > i) {
            float4 bi = sob[i];
            float Ai = sar[i];
            for (int bit = 0; bit < 64; ++bit) {
                int j = (w << 6) + bit;
                if (j <= i) continue;
                float4 bj = sob[j];
                float lt0 = fmaxf(bi.x, bj.x);
                float lt1 = fmaxf(bi.y, bj.y);
                float rb0 = fminf(bi.z, bj.z);
                float rb1 = fminf(bi.w, bj.w);
                float ww = fmaxf(rb0 - lt0, 0.0f);
                float hh = fmaxf(rb1 - lt1, 0.0f);
                float inter = ww * hh;
                float den = ((Ai + sar[j]) - inter) + 1e-7f;
                float iou = inter / den;
                if (iou > 0.45f) mword |= (1ull << bit);
            }
        }
        masks[((size_t)b * KSLOT + i) * 16 + w] = mword;
    }
}

// ---------- 5. greedy scan: live-mask skip, LDS-staged rows, early stop ----------
// Trip count = number of KEPT boxes (<= 300), not number of candidates.
// Key fact: the lowest live bit is always kept (all earlier kept rows' masks
// already applied), so each serial step commits exactly one kept box.
__global__ __launch_bounds__(64) void k_scan(const u64* __restrict__ masks,
                                             const u32* __restrict__ validf,
                                             u64* __restrict__ keep) {
    __shared__ u64 rows[KSLOT];          // 8KB: current word's 64 rows x 16 words
    int b = blockIdx.x, lane = threadIdx.x;
    const char* base = (const char*)(masks + (size_t)b * KSLOT * 16);

    // prefetch word 0's 8KB block into registers (coalesced dwordx4)
    float4 r0, r1, r2, r3, r4, r5, r6, r7;
    {
        const float4* src = (const float4*)base;
        r0 = src[0*64 + lane]; r1 = src[1*64 + lane];
        r2 = src[2*64 + lane]; r3 = src[3*64 + lane];
        r4 = src[4*64 + lane]; r5 = src[5*64 + lane];
        r6 = src[6*64 + lane]; r7 = src[7*64 + lane];
    }

    u64 kw = 0ull;       // lane l<16 owns keep word l
    u64 rem = 0ull;      // lane l<16 owns removed word l
    int kept = 0;

    for (int w = 0; w < 16; ++w) {
        // stage current word's rows into LDS
        {
            float4* dst = (float4*)rows;
            dst[0*64 + lane] = r0; dst[1*64 + lane] = r1;
            dst[2*64 + lane] = r2; dst[3*64 + lane] = r3;
            dst[4*64 + lane] = r4; dst[5*64 + lane] = r5;
            dst[6*64 + lane] = r6; dst[7*64 + lane] = r7;
        }
        u32 vf = validf[(size_t)b * KSLOT + w * 64 + lane];
        u64 valid_w = __ballot(vf != 0u);
        __syncthreads();
        // issue next word's loads (overlap with the serial scan below)
        if (w < 15) {
            const float4* src = (const float4*)(base + (size_t)(w + 1) * 8192);
            r0 = src[0*64 + lane]; r1 = src[1*64 + lane];
            r2 = src[2*64 + lane]; r3 = src[3*64 + lane];
            r4 = src[4*64 + lane]; r5 = src[5*64 + lane];
            r6 = src[6*64 + lane]; r7 = src[7*64 + lane];
        }

        u64 live = valid_w & ~__shfl(rem, w);
        while (live) {
            int i = __ffsll(live) - 1;           // lowest live slot: always kept
            if (lane == w) kw |= (1ull << i);
            u64 m = (lane < 16) ? rows[i * 16 + lane] : 0ull;
            rem |= m;
            ++kept;
            if (kept >= MAXDET) break;           // only first 300 kept are emitted
            live &= ~(__shfl(m, w) | (1ull << i));
        }
        if (kept >= MAXDET) break;
        __syncthreads();   // all lanes done reading rows before next overwrite
    }
    if (lane < 16) keep[(size_t)b * 16 + lane] = kw;
}

// ---------- 6. finalize: compact kept (ordered) into first 300 rows ----------
__global__ __launch_bounds__(1024) void k_final(const u64* __restrict__ keep,
                                                const u64* __restrict__ topk,
                                                const float* __restrict__ tb,
                                                float* __restrict__ out) {
    __shared__ u64 kw[16];
    __shared__ int pref[16];
    int b = blockIdx.x, t = threadIdx.x;
    float* ob_ = out + (size_t)b * OUT_STRIDE;
    for (int i = t; i < OUT_STRIDE; i += blockDim.x) ob_[i] = 0.0f;
    if (t < 16) kw[t] = keep[(size_t)b * 16 + t];
    __syncthreads();
    if (t == 0) {
        int s = 0;
        for (int w = 0; w < 16; ++w) { pref[w] = s; s += __popcll(kw[w]); }
    }
    __syncthreads();
    int w = t >> 6, bit = t & 63;
    bool kp = (kw[w] >> bit) & 1ull;
    if (kp) {
        u64 below = (bit == 0) ? 0ull : (kw[w] & ((1ull << bit) - 1ull));
        int rank = pref[w] + __popcll(below);
        if (rank < MAXDET) {
            size_t si = (size_t)b * KSLOT + t;
            u64 key = topk[si];
            u32 hi = (u32)(key >> 32);
            u32 lo = (u32)key;
            float score = score_from_key_hi(hi);
            float clsf = (float)(lo & 0x7Fu);
            float* o = ob_ + rank * 6;
            o[0] = tb[si*4+0]; o[1] = tb[si*4+1];
            o[2] = tb[si*4+2]; o[3] = tb[si*4+3];
            o[4] = score; o[5] = clsf;
        }
    }
}

// ---------- launch ----------
extern "C" void kernel_launch(void* const* d_in, const int* in_sizes, int n_in,
                              void* d_out, int out_size, void* d_ws, size_t ws_size,
                              hipStream_t stream) {
    const float* preds = (const float*)d_in[0];
    float* out = (float*)d_out;
    int B = in_sizes[0] / (144 * A_TOT);

    char* ws = (char*)d_ws;
    size_t off = 0;
    u64* key_raw    = (u64*)(ws + off); off += (size_t)B * A_TOT * 8;
    u64* key_sorted = (u64*)(ws + off); off += (size_t)B * NCHUNK * KSLOT * 8;
    u64* topk       = (u64*)(ws + off); off += (size_t)B * KSLOT * 8;
    float* tb       = (float*)(ws + off); off += (size_t)B * KSLOT * 4 * 4;
    float* obuf     = (float*)(ws + off); off += (size_t)B * KSLOT * 4 * 4;
    float* area     = (float*)(ws + off); off += (size_t)B * KSLOT * 4;
    u32* validf     = (u32*)(ws + off); off += (size_t)B * KSLOT * 4;
    u64* masks      = (u64*)(ws + off); off += (size_t)B * KSLOT * 16 * 8;
    u64* keep       = (u64*)(ws + off); off += (size_t)B * 16 * 8;

    k_decode<<<dim3((A_TOT + 255) / 256, B), 256, 0, stream>>>(preds, key_raw);
    k_chunksort<<<dim3(NCHUNK, B), KSLOT, 0, stream>>>(key_raw, key_sorted);
    k_merge<<<B, KSLOT, 0, stream>>>(key_sorted, topk);
    k_prep<<<dim3(KSLOT / 256, B), 256, 0, stream>>>(preds, topk, tb, obuf, area, validf);
    k_matrix<<<dim3(16, B), 256, 0, stream>>>(obuf, area, masks);
    k_scan<<<B, 64, 0, stream>>>(masks, validf, keep);
    k_final<<<B, 1024, 0, stream>>>(keep, topk, tb, out);
}

// Round 3
// 199.336 us; speedup vs baseline: 1.6253x; 1.2484x over previous
//
#include <hip/hip_runtime.h>
#include <cstdint>
#include <cstddef>

typedef unsigned long long u64;
typedef unsigned int u32;

#define A_TOT   8400
#define NCLS    80
#define KSLOT   1024
#define NCHUNK  9
#define TOPK_N  1000
#define MAXDET  300
#define OUT_STRIDE (MAXDET * 6)

// ---------- helpers ----------

// stepwise f32 sigmoid with correctly-rounded f32 exp (via f64):
// e = fl32(exp(-x)); s = 1/(1+e)   -- replicates np-f32 semantics
__device__ __forceinline__ float sig32(float x) {
#pragma clang fp contract(off)
    float e = (float)exp(-(double)x);
    float t = 1.0f + e;
    return 1.0f / t;
}

__device__ __forceinline__ u32 key_hi_from_score(float s) {
    u32 u = __float_as_uint(s);
    return (u & 0x80000000u) ? ~u : (u | 0x80000000u);
}
__device__ __forceinline__ float score_from_key_hi(u32 t) {
    u32 u = (t & 0x80000000u) ? (t ^ 0x80000000u) : ~t;
    return __uint_as_float(u);
}

// ---------- 1. decode: conf/argmax -> sort key ----------
__global__ void k_decode(const float* __restrict__ preds, u64* __restrict__ key_raw) {
#pragma clang fp contract(off)
    int a = blockIdx.x * blockDim.x + threadIdx.x;
    int b = blockIdx.y;
    if (a >= A_TOT) return;
    const float* p = preds + ((size_t)b * 144 + 64) * A_TOT + a;

    float m = -3.0e38f, m2 = -3.0e38f;
    int jm = 0;
#pragma unroll 4
    for (int c = 0; c < NCLS; ++c) {
        float v = p[(size_t)c * A_TOT];
        if (v > m) { m2 = m; m = v; jm = c; }
        else if (v > m2) { m2 = v; }
    }

    float conf;
    int cls = jm;
    if ((m - m2) < 1e-4f || m > 7.0f) {
        // slow exact path: argmax over f32 sigmoid values (first-index ties)
        float sb = -1.0f; int jb = 0;
        for (int c = 0; c < NCLS; ++c) {
            float s = sig32(p[(size_t)c * A_TOT]);
            if (s > sb) { sb = s; jb = c; }
        }
        conf = sb; cls = jb;
    } else {
        conf = sig32(m);
    }

    float score = (conf > 0.25f) ? conf : -1.0f;
    u32 hi = key_hi_from_score(score);
    u32 lo = ((0x3FFFu - (u32)a) << 7) | (u32)cls;   // idx asc tie-break + carry cls
    key_raw[(size_t)b * A_TOT + a] = ((u64)hi << 32) | lo;
}

// ---------- 2a. bitonic sort of 1024-chunks (descending) ----------
__global__ __launch_bounds__(1024) void k_chunksort(const u64* __restrict__ key_raw,
                                                    u64* __restrict__ key_sorted) {
    __shared__ u64 s[KSLOT];
    int b = blockIdx.y, ch = blockIdx.x, t = threadIdx.x;
    int a = ch * KSLOT + t;
    s[t] = (a < A_TOT) ? key_raw[(size_t)b * A_TOT + a] : 0ull;
    __syncthreads();
    for (int k = 2; k <= KSLOT; k <<= 1) {
        for (int j = k >> 1; j > 0; j >>= 1) {
            int ixj = t ^ j;
            if (ixj > t) {
                u64 x = s[t], y = s[ixj];
                bool descBlock = ((t & k) == 0);
                bool sw = descBlock ? (x < y) : (x > y);
                if (sw) { s[t] = y; s[ixj] = x; }
            }
            __syncthreads();
        }
    }
    key_sorted[((size_t)b * NCHUNK + ch) * KSLOT + t] = s[t];
}

// ---------- 2b. merge 9 sorted chunks -> top-1024 descending ----------
__global__ __launch_bounds__(1024) void k_merge(const u64* __restrict__ key_sorted,
                                                u64* __restrict__ topk) {
    __shared__ u64 R[KSLOT];
    __shared__ u64 C[KSLOT];
    int b = blockIdx.x, t = threadIdx.x;
    R[t] = key_sorted[((size_t)b * NCHUNK) * KSLOT + t];
    for (int ch = 1; ch < NCHUNK; ++ch) {
        C[t] = key_sorted[((size_t)b * NCHUNK + ch) * KSLOT + t];
        __syncthreads();
        u64 r = R[t];
        u64 c = C[(KSLOT - 1) - t];
        u64 nv = (r > c) ? r : c;       // top-1024 of union, bitonic
        __syncthreads();
        R[t] = nv;
        __syncthreads();
        for (int j = KSLOT >> 1; j >= 1; j >>= 1) {   // bitonic merge, descending
            int ixj = t ^ j;
            if (ixj > t) {
                u64 x = R[t], y = R[ixj];
                if (x < y) { R[t] = y; R[ixj] = x; }
            }
            __syncthreads();
        }
    }
    topk[(size_t)b * KSLOT + t] = R[t];
}

// ---------- 3. prep: DFL box decode for top slots, offset boxes + areas ----------
__global__ void k_prep(const float* __restrict__ preds, const u64* __restrict__ topk,
                       float* __restrict__ tb, float* __restrict__ ob,
                       float* __restrict__ area, u32* __restrict__ validf) {
#pragma clang fp contract(off)
    int slot = blockIdx.x * blockDim.x + threadIdx.x;
    int b = blockIdx.y;
    if (slot >= KSLOT) return;
    size_t si = (size_t)b * KSLOT + slot;
    u64 key = topk[si];
    u32 hi = (u32)(key >> 32);
    u32 lo = (u32)key;
    bool valid = (slot < TOPK_N) && (hi & 0x80000000u);
    if (!valid) {
        tb[si*4+0]=0.f; tb[si*4+1]=0.f; tb[si*4+2]=0.f; tb[si*4+3]=0.f;
        ob[si*4+0]=0.f; ob[si*4+1]=0.f; ob[si*4+2]=0.f; ob[si*4+3]=0.f;
        area[si] = 0.f; validf[si] = 0u;
        return;
    }
    int a   = 0x3FFF - (int)((lo >> 7) & 0x3FFFu);
    int cls = (int)(lo & 0x7Fu);

    int row, col; float stride;
    if (a < 6400)      { row = a / 80;          col = a % 80;          stride = 8.0f; }
    else if (a < 8000) { int aa = a - 6400; row = aa / 40; col = aa % 40; stride = 16.0f; }
    else               { int aa = a - 8000; row = aa / 20; col = aa % 20; stride = 32.0f; }
    float ax = (float)col + 0.5f;
    float ay = (float)row + 0.5f;

    const float* p = preds + (size_t)b * 144 * A_TOT + a;
    float d[4];
#pragma unroll
    for (int q = 0; q < 4; ++q) {
        float x[16];
#pragma unroll
        for (int r = 0; r < 16; ++r) x[r] = p[(size_t)(q*16 + r) * A_TOT];
        float mx = x[0];
#pragma unroll
        for (int r = 1; r < 16; ++r) mx = fmaxf(mx, x[r]);
        float e[16], s = 0.f;
#pragma unroll
        for (int r = 0; r < 16; ++r) { e[r] = expf(x[r] - mx); s = s + e[r]; }
        float dd = 0.f;
#pragma unroll
        for (int r = 0; r < 16; ++r) { float pr = e[r] / s; dd = dd + pr * (float)r; }
        d[q] = dd;
    }
    // exact reference op order
    float x1 = ax - d[0], y1 = ay - d[1];
    float x2 = ax + d[2], y2 = ay + d[3];
    float cx = (x1 + x2) / 2.0f, cy = (y1 + y2) / 2.0f;
    float w  = x2 - x1,          h  = y2 - y1;
    float CX = cx * stride, CY = cy * stride, W = w * stride, H = h * stride;
    float bx1 = CX - W / 2.0f, by1 = CY - H / 2.0f;
    float bx2 = CX + W / 2.0f, by2 = CY + H / 2.0f;
    tb[si*4+0] = bx1; tb[si*4+1] = by1; tb[si*4+2] = bx2; tb[si*4+3] = by2;

    float off = (float)cls * 7680.0f;
    float o0 = bx1 + off, o1 = by1 + off, o2 = bx2 + off, o3 = by2 + off;
    ob[si*4+0] = o0; ob[si*4+1] = o1; ob[si*4+2] = o2; ob[si*4+3] = o3;
    area[si] = (o2 - o0) * (o3 - o1);
    validf[si] = 1u;
}

// ---------- 4. suppression bitmask matrix: row i, bits j>i with iou>thr ----------
// Lane assignment: lanes of a wave hold consecutive i (register-resident bi),
// w is wave-uniform -> inner-loop sob[j]/sar[j] reads are LDS broadcasts
// (zero bank conflicts). Word-blocks fully below the diagonal are skipped.
__global__ __launch_bounds__(256) void k_matrix(const float* __restrict__ ob,
                                                const float* __restrict__ area,
                                                u64* __restrict__ masks) {
#pragma clang fp contract(off)
    __shared__ float4 sob[KSLOT];
    __shared__ float  sar[KSLOT];
    int b = blockIdx.y, rblk = blockIdx.x, tid = threadIdx.x;
    const float4* gob = (const float4*)(ob + (size_t)b * KSLOT * 4);
    const float*  gar = area + (size_t)b * KSLOT;
    for (int i = tid; i < KSLOT; i += blockDim.x) { sob[i] = gob[i]; sar[i] = gar[i]; }
    __syncthreads();

    int lane = tid & 63;
    int wave = tid >> 6;               // 0..3
    int i = rblk * 64 + lane;
    float4 bi = sob[i];
    float Ai = sar[i];

#pragma unroll
    for (int wl = 0; wl < 4; ++wl) {
        int w = wave * 4 + wl;         // wave-uniform word index 0..15
        u64 mword = 0ull;
        if (w >= rblk) {               // whole word below diagonal -> all zero
            for (int bit = 0; bit < 64; ++bit) {
                int j = (w << 6) + bit;
                float4 bj = sob[j];    // broadcast (uniform addr across wave)
                float Aj = sar[j];     // broadcast
                float lt0 = fmaxf(bi.x, bj.x);
                float lt1 = fmaxf(bi.y, bj.y);
                float rb0 = fminf(bi.z, bj.z);
                float rb1 = fminf(bi.w, bj.w);
                float ww = fmaxf(rb0 - lt0, 0.0f);
                float hh = fmaxf(rb1 - lt1, 0.0f);
                float inter = ww * hh;
                float den = ((Ai + Aj) - inter) + 1e-7f;
                float iou = inter / den;
                if ((j > i) && (iou > 0.45f)) mword |= (1ull << bit);
            }
        }
        masks[((size_t)b * KSLOT + i) * 16 + w] = mword;
    }
}

// ---------- 5. greedy scan: live-mask skip, LDS-staged rows, early stop ----------
// Trip count = number of KEPT boxes (<= 300), not number of candidates.
// Key fact: the lowest live bit is always kept (all earlier kept rows' masks
// already applied), so each serial step commits exactly one kept box.
__global__ __launch_bounds__(64) void k_scan(const u64* __restrict__ masks,
                                             const u32* __restrict__ validf,
                                             u64* __restrict__ keep) {
    __shared__ u64 rows[KSLOT];          // 8KB: current word's 64 rows x 16 words
    int b = blockIdx.x, lane = threadIdx.x;
    const char* base = (const char*)(masks + (size_t)b * KSLOT * 16);

    // prefetch word 0's 8KB block into registers (coalesced dwordx4)
    float4 r0, r1, r2, r3, r4, r5, r6, r7;
    {
        const float4* src = (const float4*)base;
        r0 = src[0*64 + lane]; r1 = src[1*64 + lane];
        r2 = src[2*64 + lane]; r3 = src[3*64 + lane];
        r4 = src[4*64 + lane]; r5 = src[5*64 + lane];
        r6 = src[6*64 + lane]; r7 = src[7*64 + lane];
    }

    u64 kw = 0ull;       // lane l<16 owns keep word l
    u64 rem = 0ull;      // lane l<16 owns removed word l
    int kept = 0;

    for (int w = 0; w < 16; ++w) {
        // stage current word's rows into LDS
        {
            float4* dst = (float4*)rows;
            dst[0*64 + lane] = r0; dst[1*64 + lane] = r1;
            dst[2*64 + lane] = r2; dst[3*64 + lane] = r3;
            dst[4*64 + lane] = r4; dst[5*64 + lane] = r5;
            dst[6*64 + lane] = r6; dst[7*64 + lane] = r7;
        }
        u32 vf = validf[(size_t)b * KSLOT + w * 64 + lane];
        u64 valid_w = __ballot(vf != 0u);
        __syncthreads();
        // issue next word's loads (overlap with the serial scan below)
        if (w < 15) {
            const float4* src = (const float4*)(base + (size_t)(w + 1) * 8192);
            r0 = src[0*64 + lane]; r1 = src[1*64 + lane];
            r2 = src[2*64 + lane]; r3 = src[3*64 + lane];
            r4 = src[4*64 + lane]; r5 = src[5*64 + lane];
            r6 = src[6*64 + lane]; r7 = src[7*64 + lane];
        }

        u64 live = valid_w & ~__shfl(rem, w);
        while (live) {
            int i = __ffsll(live) - 1;           // lowest live slot: always kept
            if (lane == w) kw |= (1ull << i);
            u64 m = (lane < 16) ? rows[i * 16 + lane] : 0ull;
            rem |= m;
            ++kept;
            if (kept >= MAXDET) break;           // only first 300 kept are emitted
            live &= ~(__shfl(m, w) | (1ull << i));
        }
        if (kept >= MAXDET) break;
        __syncthreads();   // all lanes done reading rows before next overwrite
    }
    if (lane < 16) keep[(size_t)b * 16 + lane] = kw;
}

// ---------- 6. finalize: compact kept (ordered) into first 300 rows ----------
__global__ __launch_bounds__(1024) void k_final(const u64* __restrict__ keep,
                                                const u64* __restrict__ topk,
                                                const float* __restrict__ tb,
                                                float* __restrict__ out) {
    __shared__ u64 kw[16];
    __shared__ int pref[16];
    int b = blockIdx.x, t = threadIdx.x;
    float* ob_ = out + (size_t)b * OUT_STRIDE;
    for (int i = t; i < OUT_STRIDE; i += blockDim.x) ob_[i] = 0.0f;
    if (t < 16) kw[t] = keep[(size_t)b * 16 + t];
    __syncthreads();
    if (t == 0) {
        int s = 0;
        for (int w = 0; w < 16; ++w) { pref[w] = s; s += __popcll(kw[w]); }
    }
    __syncthreads();
    int w = t >> 6, bit = t & 63;
    bool kp = (kw[w] >> bit) & 1ull;
    if (kp) {
        u64 below = (bit == 0) ? 0ull : (kw[w] & ((1ull << bit) - 1ull));
        int rank = pref[w] + __popcll(below);
        if (rank < MAXDET) {
            size_t si = (size_t)b * KSLOT + t;
            u64 key = topk[si];
            u32 hi = (u32)(key >> 32);
            u32 lo = (u32)key;
            float score = score_from_key_hi(hi);
            float clsf = (float)(lo & 0x7Fu);
            float* o = ob_ + rank * 6;
            o[0] = tb[si*4+0]; o[1] = tb[si*4+1];
            o[2] = tb[si*4+2]; o[3] = tb[si*4+3];
            o[4] = score; o[5] = clsf;
        }
    }
}

// ---------- launch ----------
extern "C" void kernel_launch(void* const* d_in, const int* in_sizes, int n_in,
                              void* d_out, int out_size, void* d_ws, size_t ws_size,
                              hipStream_t stream) {
    const float* preds = (const float*)d_in[0];
    float* out = (float*)d_out;
    int B = in_sizes[0] / (144 * A_TOT);

    char* ws = (char*)d_ws;
    size_t off = 0;
    u64* key_raw    = (u64*)(ws + off); off += (size_t)B * A_TOT * 8;
    u64* key_sorted = (u64*)(ws + off); off += (size_t)B * NCHUNK * KSLOT * 8;
    u64* topk       = (u64*)(ws + off); off += (size_t)B * KSLOT * 8;
    float* tb       = (float*)(ws + off); off += (size_t)B * KSLOT * 4 * 4;
    float* obuf     = (float*)(ws + off); off += (size_t)B * KSLOT * 4 * 4;
    float* area     = (float*)(ws + off); off += (size_t)B * KSLOT * 4;
    u32* validf     = (u32*)(ws + off); off += (size_t)B * KSLOT * 4;
    u64* masks      = (u64*)(ws + off); off += (size_t)B * KSLOT * 16 * 8;
    u64* keep       = (u64*)(ws + off); off += (size_t)B * 16 * 8;

    k_decode<<<dim3((A_TOT + 255) / 256, B), 256, 0, stream>>>(preds, key_raw);
    k_chunksort<<<dim3(NCHUNK, B), KSLOT, 0, stream>>>(key_raw, key_sorted);
    k_merge<<<B, KSLOT, 0, stream>>>(key_sorted, topk);
    k_prep<<<dim3(KSLOT / 256, B), 256, 0, stream>>>(preds, topk, tb, obuf, area, validf);
    k_matrix<<<dim3(16, B), 256, 0, stream>>>(obuf, area, masks);
    k_scan<<<B, 64, 0, stream>>>(masks, validf, keep);
    k_final<<<B, 1024, 0, stream>>>(keep, topk, tb, out);
}